// Round 5
// baseline (135.916 us; speedup 1.0000x reference)
//
#include <hip/hip_runtime.h>

#define B_      128
#define C_IN_   256
#define NPTS    1024
#define C_OUT_  256
#define L_      3069
#define NTRIP   1023
#define T_OUT   1024
#define FEATS_SIZE (B_ * C_OUT_ * T_OUT)
#define KTOT    768

#define THREADS 512

typedef __attribute__((ext_vector_type(8))) short           bf16x8;
typedef __attribute__((ext_vector_type(8))) unsigned short  ushort8;
typedef __attribute__((ext_vector_type(4))) unsigned short  ushort4v;
typedef __attribute__((ext_vector_type(4))) float           f32x4;

__device__ __forceinline__ unsigned short f2bf(float f) {
    union { float f; unsigned u; } v; v.f = f;
    unsigned r = (v.u + 0x7FFFu + ((v.u >> 16) & 1u)) >> 16;   // RNE
    return (unsigned short)r;
}

__device__ __forceinline__ void gload16(const void* g, void* l) {
    __builtin_amdgcn_global_load_lds(
        (const __attribute__((address_space(1))) unsigned int*)g,
        (__attribute__((address_space(3))) unsigned int*)l, 16, 0, 0);
}

// ===================== TIER 2 (fast path) =====================
// K = 24 slices of 32 (slice s: tap t = s>>3, channel block cb = s&7).
//
// A (weights) NEVER touches LDS: fragment-major table wbf5, bf16 index
//   i = ((s*256 + row)*32 + lg*8 + e)  holds  W[row][(cb*32+lg*8+e)*3 + t].
// Lane (l15,lg) of wave wm reads frag mi as ONE dwordx4 at byte
//   s*16384 + (wm*64+mi*16+l15)*64 + lg*16   (1 KB/instr, coalesced, L2-hot).
// Prefetched 2 slices ahead into a 3-bank register ring.
//
// B slice image in LDS: 128 rows x 64 B, slot-XOR (j ^ (n&3)); staged by
// gload16 (linear dest, gather in SOURCE offset), 6-deep pipeline.
//
// SYNC DISCIPLINE (R4 post-mortem): normal loads (ALOAD) and gload16 can be
// reordered by the compiler (different addr spaces, no alias). Every region
// is therefore fenced: [4x ALOAD][fence][1x BSTAGE], making BSTAGE the LAST
// vmem op of its body. vmcnt counts below are exact for that order.
//
// ws: [0, 393216): wbf5 ; [393216, +67108864): dataT bf16 [b][n][c]
#define WOFF_T  0
#define DOFF_T  393216
#define WS_NEED_T2 (393216 + 67108864)

#define NSLICE  24
#define BBYTES  8192
#define NBUF    6
#define IDX5    (NBUF * BBYTES)        // 49152
#define SMEM5   (IDX5 + 1536)          // 50688
#define BN2     128

#define WAITV(n) asm volatile("s_waitcnt vmcnt(" #n ")" ::: "memory")
#define MEMFENCE asm volatile("" ::: "memory")

// weight fp32 -> bf16, slice-major fragment layout (A path, no swizzle)
__global__ __launch_bounds__(256) void convert_w5(
    const float* __restrict__ w, unsigned short* __restrict__ wbf5)
{
    int i = blockIdx.x * 256 + threadIdx.x;          // 0 .. 196607
    if (i >= C_OUT_ * KTOT) return;
    int e  = i & 7;
    int lg = (i >> 3) & 3;
    int r  = (i >> 5) & 255;
    int s  = i >> 13;           // 0..23
    int t  = s >> 3;
    int cb = s & 7;
    int c  = cb * 32 + lg * 8 + e;
    wbf5[i] = f2bf(w[r * KTOT + c * 3 + t]);
}

// data fp32 [b][c][n] -> dataT bf16 [b][n][c]
__global__ __launch_bounds__(256) void transpose_data(
    const float* __restrict__ data, unsigned short* __restrict__ dataT)
{
    __shared__ float T[64][68];
    const int bid = blockIdx.x;
    const int b   = bid >> 6;
    const int ct  = (bid & 63) >> 4;     // 0..3
    const int nt  = bid & 15;            // 0..15
    const int c0  = ct * 64, n0 = nt * 64;
    const int t   = threadIdx.x;
    const int row = t >> 2;              // 0..63
    const int q   = t & 3;

    const float* src = data + ((size_t)(b * C_IN_ + c0 + row)) * NPTS + n0 + q * 16;
    #pragma unroll
    for (int j = 0; j < 4; ++j) {
        float4 v = *(const float4*)(src + j * 4);
        *(float4*)&T[row][q * 16 + j * 4] = v;
    }
    __syncthreads();

    ushort8 o0, o1;
    #pragma unroll
    for (int j = 0; j < 8; ++j)  o0[j] = f2bf(T[q * 16 + j][row]);
    #pragma unroll
    for (int j = 0; j < 8; ++j)  o1[j] = f2bf(T[q * 16 + 8 + j][row]);
    unsigned short* dst = dataT + ((size_t)(b * NPTS) + n0 + row) * C_IN_ + c0 + q * 16;
    *(ushort8*)(dst)     = o0;
    *(ushort8*)(dst + 8) = o1;
}

// 8 waves as 4(m) x 2(n); per-wave output tile 64x64 (mi=4, ni=4).
// 1 block/CU by design: pipeline depth over TLP.
__global__ __launch_bounds__(THREADS, 2) void treeconv_mfma5(
    const unsigned short* __restrict__ wbf5,
    const unsigned short* __restrict__ dataT,
    const int*   __restrict__ indexes,
    const float* __restrict__ bias,
    float*       __restrict__ out)
{
    __shared__ alignas(16) unsigned char smem[SMEM5];
    int* idx_s = (int*)(smem + IDX5);

    const int tid = threadIdx.x;
    // bijective XCD swizzle: the 8 n-tiles of one batch share one XCD's L2
    const int wg  = (blockIdx.x & 7) * 128 + (blockIdx.x >> 3);
    const int b   = wg >> 3;
    const int nt0 = (wg & 7) * BN2;

    if (tid < BN2 * 3) {
        int off = nt0 * 3 + tid;
        idx_s[tid] = (off < L_) ? indexes[b * L_ + off] : 0;
    }
    __syncthreads();

    const int lane = tid & 63;
    const int wid  = tid >> 6;
    const int wm   = wid >> 1;     // m base = wm*64
    const int wn   = wid & 1;      // n base = wn*64
    const int l15  = lane & 15;
    const int lg   = lane >> 4;

    // ---- B stage gather offsets (one 16B slot per thread) ----
    // image (n = slot>>2, j = slot&3) holds channel-group lgp = j ^ (n&3)
    const int slotB = wid * 64 + lane;
    const int nB    = slotB >> 2;
    const int lgp   = (slotB & 3) ^ (nB & 3);
    const unsigned boff0 = (unsigned)(idx_s[nB * 3 + 0] * 512 + lgp * 16);
    const unsigned boff1 = (unsigned)(idx_s[nB * 3 + 1] * 512 + lgp * 16);
    const unsigned boff2 = (unsigned)(idx_s[nB * 3 + 2] * 512 + lgp * 16);

    const char* dTb  = (const char*)dataT + (size_t)b * NPTS * C_IN_ * 2;
    const char* wsrc = (const char*)wbf5;
    const int   awoff = (wm * 64 + l15) * 64 + lg * 16;   // A frag lane offset
    unsigned char* bdst0 = smem + slotB * 16;             // + buf*BBYTES

    // fragment read base for B (slot-XOR: row&3 == l15&3, lane-constant)
    const unsigned xsl   = (unsigned)((lg ^ (l15 & 3)) << 4);
    const unsigned bbase = (unsigned)((wn * 64 + l15) * 64) + xsl;

    f32x4 acc[4][4];
    #pragma unroll
    for (int mi = 0; mi < 4; ++mi)
        #pragma unroll
        for (int ni = 0; ni < 4; ++ni)
            acc[mi][ni] = (f32x4){0.f, 0.f, 0.f, 0.f};

#define BSTAGE(s) do {                                                        \
        unsigned bo = ((s) < 8 ? boff0 : (s) < 16 ? boff1 : boff2)            \
                      + (unsigned)(((s) & 7) * 64);                           \
        gload16(dTb + bo, bdst0 + ((s) % NBUF) * BBYTES);                     \
    } while (0)

#define ALOAD(s, dst) do {                                                    \
        const char* ap_ = wsrc + (s) * 16384 + awoff;                         \
        dst[0] = *(const bf16x8*)(ap_);                                       \
        dst[1] = *(const bf16x8*)(ap_ + 1024);                                \
        dst[2] = *(const bf16x8*)(ap_ + 2048);                                \
        dst[3] = *(const bf16x8*)(ap_ + 3072);                                \
    } while (0)

    bf16x8 areg[3][4];

    // prologue vmem order (fenced): A(0) A(1) [8 ops] | B0 B1 B2 B3 B4
    ALOAD(0, areg[0]);
    ALOAD(1, areg[1]);
    MEMFENCE;
    BSTAGE(0); BSTAGE(1); BSTAGE(2); BSTAGE(3); BSTAGE(4);

    #pragma unroll
    for (int s = 0; s < NSLICE; ++s) {
        // Exact ops-after-B(s) for the fenced order ([4xALOAD][fence][BSTAGE]
        // per body, BSTAGE last):
        //   s=0: B1..B4                                   = 4
        //   s=1: B2..B4 + body0(5)                        = 8
        //   s=2: 2 + 10                                   = 12
        //   s=3: 1 + 15                                   = 16
        //   s=4..19: 4 full bodies x5 (B(s) ends body s-5)= 20
        //   s=20: 15 + body19(4, no BSTAGE)               = 19
        //   s=21: 10 + 4 + 4                              = 18
        //   s=22: 5 + 4 + 4 + 4                           = 17
        //   s=23: 4 + 4 + 4 + 0(body22 empty)             = 12
        if      (s == 0)  WAITV(4);
        else if (s == 1)  WAITV(8);
        else if (s == 2)  WAITV(12);
        else if (s == 3)  WAITV(16);
        else if (s <= 19) WAITV(20);
        else if (s == 20) WAITV(19);
        else if (s == 21) WAITV(18);
        else if (s == 22) WAITV(17);
        else              WAITV(12);
        __builtin_amdgcn_s_barrier();

        const unsigned char* bufp = smem + (s % NBUF) * BBYTES;
        bf16x8 bb[4];
        #pragma unroll
        for (int ni = 0; ni < 4; ++ni)
            bb[ni] = *(const bf16x8*)(bufp + bbase + ni * 1024);

        // A prefetch 2 ahead into ring bank (s+2)%3 (banks s%3,(s+1)%3 live)
        if (s + 2 < NSLICE) ALOAD(s + 2, areg[(s + 2) % 3]);
        MEMFENCE;
        // B stage 5 ahead -> buf (s+5)%6 == (s-1)%6; safe: every wave passed
        // this slice's barrier only after consuming slice s-1's ds_reads.
        if (s + 5 < NSLICE) BSTAGE(s + 5);

        #pragma unroll
        for (int mi = 0; mi < 4; ++mi)
            #pragma unroll
            for (int ni = 0; ni < 4; ++ni)
                acc[mi][ni] = __builtin_amdgcn_mfma_f32_16x16x32_bf16(
                    areg[s % 3][mi], bb[ni], acc[mi][ni], 0, 0, 0);
    }
#undef BSTAGE
#undef ALOAD

    float* outB = out + (size_t)b * (C_OUT_ * T_OUT);
    #pragma unroll
    for (int mi = 0; mi < 4; ++mi) {
        #pragma unroll
        for (int r = 0; r < 4; ++r) {
            int o = wm * 64 + mi * 16 + lg * 4 + r;
            float bv = bias[o];
            #pragma unroll
            for (int ni = 0; ni < 4; ++ni) {
                int n = nt0 + wn * 64 + ni * 16 + l15;
                if (n < NTRIP)
                    outB[o * T_OUT + 1 + n] = acc[mi][ni][r] + bv;
            }
        }
    }
}

// ===================== TIER 1/0 (round-2 fallback) =====================
#define BN      64
#define BK      96
#define NCHUNK  8
#define AS_OFF  0
#define BS_OFF  49152
#define IDX_OFF 61440
#define SMEM_BYTES 62208

template<bool PREW>
__global__ __launch_bounds__(THREADS, 4) void treeconv_mfma(
    const float* __restrict__ data,
    const int*   __restrict__ indexes,
    const float* __restrict__ w32,
    const unsigned short* __restrict__ wbf,
    const float* __restrict__ bias,
    float*       __restrict__ out)
{
    __shared__ alignas(16) unsigned char smem[SMEM_BYTES];
    int* idx_s = (int*)(smem + IDX_OFF);

    const int tid = threadIdx.x;
    const int b   = blockIdx.x >> 4;
    const int nt0 = (blockIdx.x & 15) * BN;

    if (tid < BN * 3) {
        int off = nt0 * 3 + tid;
        idx_s[tid] = (off < L_) ? indexes[b * L_ + off] : 0;
    }
    __syncthreads();

    const int lane = tid & 63;
    const int wid  = tid >> 6;
    const int wm   = wid >> 1;
    const int wn   = wid & 1;
    const int l15  = lane & 15;
    const int lg   = lane >> 4;

    f32x4 acc[4][2];
    #pragma unroll
    for (int mi = 0; mi < 4; ++mi)
        #pragma unroll
        for (int ni = 0; ni < 2; ++ni)
            acc[mi][ni] = (f32x4){0.f, 0.f, 0.f, 0.f};

    const float* dataB = data + (size_t)b * (C_IN_ * NPTS);
    const int ar = tid >> 1;
    const int ah = tid & 1;
    const int gn = tid & 63;
    const int g8 = tid >> 6;

    for (int kc = 0; kc < NCHUNK; ++kc) {
        {
            const int ab = ar * 192 + ah * 96;
            const int sw = (ar & 7) << 4;
            if (PREW) {
                const ushort8* src = (const ushort8*)(wbf + ar * KTOT + kc * BK + ah * 48);
                #pragma unroll
                for (int j = 0; j < 6; ++j) {
                    ushort8 v = src[j];
                    *(ushort8*)(smem + ((ab + j * 16) ^ sw)) = v;
                }
            } else {
                const float* src = w32 + ar * KTOT + kc * BK + ah * 48;
                #pragma unroll
                for (int j = 0; j < 6; ++j) {
                    float4 fa = *(const float4*)(src + j * 8);
                    float4 fb = *(const float4*)(src + j * 8 + 4);
                    ushort8 v;
                    v[0] = f2bf(fa.x); v[1] = f2bf(fa.y); v[2] = f2bf(fa.z); v[3] = f2bf(fa.w);
                    v[4] = f2bf(fb.x); v[5] = f2bf(fb.y); v[6] = f2bf(fb.z); v[7] = f2bf(fb.w);
                    *(ushort8*)(smem + ((ab + j * 16) ^ sw)) = v;
                }
            }
        }
        {
            const int* ip = idx_s + gn * 3;
            int ix0 = ip[0], ix1 = ip[1], ix2 = ip[2];
            const float* dp = dataB + (kc * 32 + g8 * 4) * NPTS;
            unsigned short vals[12];
            #pragma unroll
            for (int ci = 0; ci < 4; ++ci) {
                vals[ci * 3 + 0] = f2bf(dp[ix0]);
                vals[ci * 3 + 1] = f2bf(dp[ix1]);
                vals[ci * 3 + 2] = f2bf(dp[ix2]);
                dp += NPTS;
            }
            const int bb = BS_OFF + gn * 192 + g8 * 24;
            const int sw = (gn & 7) << 4;
            #pragma unroll
            for (int q = 0; q < 3; ++q) {
                ushort4v v;
                v[0] = vals[q * 4 + 0]; v[1] = vals[q * 4 + 1];
                v[2] = vals[q * 4 + 2]; v[3] = vals[q * 4 + 3];
                *(ushort4v*)(smem + ((bb + q * 8) ^ sw)) = v;
            }
        }
        __syncthreads();

        #pragma unroll
        for (int ks = 0; ks < 3; ++ks) {
            bf16x8 a[4], bf[2];
            const int kb = ks * 64 + lg * 16;
            #pragma unroll
            for (int mi = 0; mi < 4; ++mi) {
                int row = wm * 64 + mi * 16 + l15;
                a[mi] = *(const bf16x8*)(smem + ((row * 192 + kb) ^ ((row & 7) << 4)));
            }
            #pragma unroll
            for (int ni = 0; ni < 2; ++ni) {
                int row = wn * 32 + ni * 16 + l15;
                bf[ni] = *(const bf16x8*)(smem + ((BS_OFF + row * 192 + kb) ^ ((row & 7) << 4)));
            }
            #pragma unroll
            for (int mi = 0; mi < 4; ++mi)
                #pragma unroll
                for (int ni = 0; ni < 2; ++ni)
                    acc[mi][ni] = __builtin_amdgcn_mfma_f32_16x16x32_bf16(
                        a[mi], bf[ni], acc[mi][ni], 0, 0, 0);
        }
        __syncthreads();
    }

    float* outB = out + (size_t)b * (C_OUT_ * T_OUT);
    #pragma unroll
    for (int mi = 0; mi < 4; ++mi) {
        #pragma unroll
        for (int r = 0; r < 4; ++r) {
            int o = wm * 64 + mi * 16 + lg * 4 + r;
            float bv = bias[o];
            #pragma unroll
            for (int ni = 0; ni < 2; ++ni) {
                int n = nt0 + wn * 32 + ni * 16 + l15;
                if (n < NTRIP)
                    outB[o * T_OUT + 1 + n] = acc[mi][ni][r] + bv;
            }
        }
    }
}

__global__ __launch_bounds__(256) void convert_w(
    const float* __restrict__ w, unsigned short* __restrict__ wbf)
{
    int i = (blockIdx.x * 256 + threadIdx.x) * 4;
    if (i < C_OUT_ * KTOT) {
        float4 f = *(const float4*)(w + i);
        ushort4v v;
        v[0] = f2bf(f.x); v[1] = f2bf(f.y); v[2] = f2bf(f.z); v[3] = f2bf(f.w);
        *(ushort4v*)(wbf + i) = v;
    }
}

__global__ __launch_bounds__(256) void aux_kernel(
    const int* __restrict__ indexes, float* __restrict__ out)
{
    int i = blockIdx.x * 256 + threadIdx.x;
    if (i < B_ * L_)
        out[FEATS_SIZE + i] = (float)indexes[i];
    if (i < B_ * C_OUT_)
        out[(size_t)i * T_OUT] = 0.0f;
}

extern "C" void kernel_launch(void* const* d_in, const int* in_sizes, int n_in,
                              void* d_out, int out_size, void* d_ws, size_t ws_size,
                              hipStream_t stream)
{
    const float* data    = (const float*)d_in[0];
    const int*   indexes = (const int*)d_in[1];
    const float* weight  = (const float*)d_in[2];
    const float* bias    = (const float*)d_in[3];
    float* out = (float*)d_out;

    hipLaunchKernelGGL(aux_kernel, dim3((B_ * L_ + 255) / 256), dim3(256), 0, stream,
                       indexes, out);

    if (ws_size >= (size_t)WS_NEED_T2) {
        unsigned short* wbf5  = (unsigned short*)((char*)d_ws + WOFF_T);
        unsigned short* dataT = (unsigned short*)((char*)d_ws + DOFF_T);
        hipLaunchKernelGGL(convert_w5, dim3((C_OUT_ * KTOT + 255) / 256), dim3(256),
                           0, stream, weight, wbf5);
        hipLaunchKernelGGL(transpose_data, dim3(B_ * 64), dim3(256), 0, stream,
                           data, dataT);
        hipLaunchKernelGGL(treeconv_mfma5, dim3(B_ * 8), dim3(THREADS), 0, stream,
                           wbf5, dataT, indexes, bias, out);
    } else if (ws_size >= (size_t)(C_OUT_ * KTOT * 2)) {
        unsigned short* wbf = (unsigned short*)d_ws;
        hipLaunchKernelGGL(convert_w, dim3((C_OUT_ * KTOT / 4 + 255) / 256), dim3(256),
                           0, stream, weight, wbf);
        hipLaunchKernelGGL((treeconv_mfma<true>), dim3(B_ * 16), dim3(THREADS), 0, stream,
                           data, indexes, weight, wbf, bias, out);
    } else {
        hipLaunchKernelGGL((treeconv_mfma<false>), dim3(B_ * 16), dim3(THREADS), 0, stream,
                           data, indexes, weight, (const unsigned short*)d_ws, bias, out);
    }
}

// Round 6
// 116.925 us; speedup vs baseline: 1.1624x; 1.1624x over previous
//
#include <hip/hip_runtime.h>

#define B_      128
#define C_IN_   256
#define NPTS    1024
#define C_OUT_  256
#define L_      3069
#define NTRIP   1023
#define T_OUT   1024
#define FEATS_SIZE (B_ * C_OUT_ * T_OUT)
#define KTOT    768

#define THREADS 512

typedef __attribute__((ext_vector_type(8))) short           bf16x8;
typedef __attribute__((ext_vector_type(8))) unsigned short  ushort8;
typedef __attribute__((ext_vector_type(4))) unsigned short  ushort4v;
typedef __attribute__((ext_vector_type(4))) float           f32x4;

__device__ __forceinline__ unsigned short f2bf(float f) {
    union { float f; unsigned u; } v; v.f = f;
    unsigned r = (v.u + 0x7FFFu + ((v.u >> 16) & 1u)) >> 16;   // RNE
    return (unsigned short)r;
}

__device__ __forceinline__ void gload16(const void* g, void* l) {
    __builtin_amdgcn_global_load_lds(
        (const __attribute__((address_space(1))) unsigned int*)g,
        (__attribute__((address_space(3))) unsigned int*)l, 16, 0, 0);
}

// ===================== TIER 2 (fast path) =====================
// K decomposed into 24 slices of 32: slice s = (tap t = s>>3, channel block
// cb = s&7, channels cb*32..+31).  A slice image: 256 rows x 64 B, slot-XOR
// swizzled: row r, 16B-slot j holds channels for lg = j ^ (r&3).  B slice
// image: 128 rows x 64 B, same swizzle.  All fragment ds_read_b128 are
// perfect 1KB permutations -> conflict-free.  Stages are LINEAR dest
// (global_load_lds); the permutation lives in the SOURCE (convert_w4 for A,
// per-slot gather offset for B).
//
// ws: [0, 393216): wbf4 — weights bf16, slice-major pre-swizzled
//     [393216, +67108864): dataT — bf16 [b][n][c]
#define WOFF_T  0
#define DOFF_T  393216
#define WS_NEED_T2 (393216 + 67108864)

#define NSLICE  24
#define ABYTES  16384
#define BBYTES  8192
#define BUFSZ   (ABYTES + BBYTES)      // 24576
#define SMEM4   (3 * BUFSZ)            // 73728
#define IDX4    (2 * BUFSZ)            // idx overlay in buf2 (prologue only)
#define BN2     128

// weight fp32 -> bf16, slice-major fragment layout, slot-XOR pre-applied
__global__ __launch_bounds__(256) void convert_w4(
    const float* __restrict__ w, unsigned short* __restrict__ wbf4)
{
    int i = blockIdx.x * 256 + threadIdx.x;          // 0 .. 196607
    if (i >= C_OUT_ * KTOT) return;
    int e  = i & 7;
    int j  = (i >> 3) & 3;
    int r  = (i >> 5) & 255;
    int s  = i >> 13;           // 0..23
    int t  = s >> 3;
    int cb = s & 7;
    int lgp = j ^ (r & 3);
    int c  = cb * 32 + lgp * 8 + e;
    wbf4[i] = f2bf(w[r * KTOT + c * 3 + t]);
}

// data fp32 [b][c][n] -> dataT bf16 [b][n][c]
__global__ __launch_bounds__(256) void transpose_data(
    const float* __restrict__ data, unsigned short* __restrict__ dataT)
{
    __shared__ float T[64][68];
    const int bid = blockIdx.x;
    const int b   = bid >> 6;
    const int ct  = (bid & 63) >> 4;     // 0..3
    const int nt  = bid & 15;            // 0..15
    const int c0  = ct * 64, n0 = nt * 64;
    const int t   = threadIdx.x;
    const int row = t >> 2;              // 0..63
    const int q   = t & 3;

    const float* src = data + ((size_t)(b * C_IN_ + c0 + row)) * NPTS + n0 + q * 16;
    #pragma unroll
    for (int j = 0; j < 4; ++j) {
        float4 v = *(const float4*)(src + j * 4);
        *(float4*)&T[row][q * 16 + j * 4] = v;
    }
    __syncthreads();

    ushort8 o0, o1;
    #pragma unroll
    for (int j = 0; j < 8; ++j)  o0[j] = f2bf(T[q * 16 + j][row]);
    #pragma unroll
    for (int j = 0; j < 8; ++j)  o1[j] = f2bf(T[q * 16 + 8 + j][row]);
    unsigned short* dst = dataT + ((size_t)(b * NPTS) + n0 + row) * C_IN_ + c0 + q * 16;
    *(ushort8*)(dst)     = o0;
    *(ushort8*)(dst + 8) = o1;
}

// 8 waves as 4(m) x 2(n); per-wave output tile 64x64 (mi=4, ni=4).
// Triple-buffered LDS pipeline, counted vmcnt, raw barriers, setprio on MFMA.
__global__ __launch_bounds__(THREADS, 4) void treeconv_mfma4(
    const unsigned short* __restrict__ wbf4,
    const unsigned short* __restrict__ dataT,
    const int*   __restrict__ indexes,
    const float* __restrict__ bias,
    float*       __restrict__ out)
{
    __shared__ alignas(16) unsigned char smem[SMEM4];
    int* idx_s = (int*)(smem + IDX4);

    const int tid = threadIdx.x;
    // bijective XCD swizzle (1024 = 8 XCD * 128): batch's 8 n-tiles share one XCD L2
    const int wg  = (blockIdx.x & 7) * 128 + (blockIdx.x >> 3);
    const int b   = wg >> 3;
    const int nt0 = (wg & 7) * BN2;

    if (tid < BN2 * 3) {
        int off = nt0 * 3 + tid;
        idx_s[tid] = (off < L_) ? indexes[b * L_ + off] : 0;
    }
    __syncthreads();

    const int lane = tid & 63;
    const int wid  = tid >> 6;
    const int wm   = wid >> 1;     // m base = wm*64
    const int wn   = wid & 1;      // n base = wn*64
    const int l15  = lane & 15;
    const int lg   = lane >> 4;

    // ---- B stage gather offsets, one 16B slot per thread ----
    // slot = wid*64+lane; image (n = slot>>2, j = slot&3) holds channels for
    // lgp = j ^ (n&3) of point ix[n*3 + t].
    const int slotB = wid * 64 + lane;
    const int nB    = slotB >> 2;
    const int lgp   = (slotB & 3) ^ (nB & 3);
    const unsigned boff0 = (unsigned)(idx_s[nB * 3 + 0] * 512 + lgp * 16);
    const unsigned boff1 = (unsigned)(idx_s[nB * 3 + 1] * 512 + lgp * 16);
    const unsigned boff2 = (unsigned)(idx_s[nB * 3 + 2] * 512 + lgp * 16);
    const int bdst = ABYTES + slotB * 16;

    const char* dTb  = (const char*)dataT + (size_t)b * NPTS * C_IN_ * 2;
    const char* wsrc = (const char*)wbf4;
    const int   a0   = (wid * 128 + lane) * 16;     // A stage: 2 slots/thread

    // fragment read bases (slot-XOR: r&3 == l15&3, lane-constant)
    const unsigned xsl   = (unsigned)((lg ^ (l15 & 3)) << 4);
    const unsigned abase = (unsigned)((wm * 64 + l15) * 64) + xsl;
    const unsigned bbase = (unsigned)(ABYTES + (wn * 64 + l15) * 64) + xsl;

    f32x4 acc[4][4];
    #pragma unroll
    for (int mi = 0; mi < 4; ++mi)
        #pragma unroll
        for (int ni = 0; ni < 4; ++ni)
            acc[mi][ni] = (f32x4){0.f, 0.f, 0.f, 0.f};

#define STAGE4(s, buf) do {                                                   \
        gload16(wsrc + (s) * ABYTES + a0,        smem + (buf) * BUFSZ + a0);  \
        gload16(wsrc + (s) * ABYTES + a0 + 1024, smem + (buf) * BUFSZ + a0 + 1024); \
        unsigned bo = (((s) >> 3) == 0 ? boff0 : ((s) >> 3) == 1 ? boff1 : boff2) \
                      + (unsigned)(((s) & 7) * 64);                           \
        gload16(dTb + bo, smem + (buf) * BUFSZ + bdst);                       \
    } while (0)

    // prologue: slices 0,1 in flight (6 loads outstanding)
    STAGE4(0, 0);
    STAGE4(1, 1);

    #pragma unroll
    for (int s = 0; s < NSLICE; ++s) {
        // outstanding: {s, s+1} (6). Wait slice s done, keep s+1 in flight.
        if (s == NSLICE - 1) asm volatile("s_waitcnt vmcnt(0)" ::: "memory");
        else                 asm volatile("s_waitcnt vmcnt(3)" ::: "memory");
        __builtin_amdgcn_s_barrier();
        asm volatile("" ::: "memory");

        const unsigned char* bufp = smem + (s % 3) * BUFSZ;
        bf16x8 a[4], bb[4];
        #pragma unroll
        for (int mi = 0; mi < 4; ++mi)
            a[mi] = *(const bf16x8*)(bufp + abase + mi * 1024);
        #pragma unroll
        for (int ni = 0; ni < 4; ++ni)
            bb[ni] = *(const bf16x8*)(bufp + bbase + ni * 1024);

        // issue stage of slice s+2 (overwrites buf (s+2)%3 == (s-1)%3; all
        // waves are past the barrier, so slice s-1 reads are complete)
        if (s + 2 < NSLICE) STAGE4(s + 2, (s + 2) % 3);

        // T5: favor MFMA-phase waves on the CU scheduler while other waves
        // are still in their ds_read/stage phase.
        __builtin_amdgcn_s_setprio(1);
        #pragma unroll
        for (int mi = 0; mi < 4; ++mi)
            #pragma unroll
            for (int ni = 0; ni < 4; ++ni)
                acc[mi][ni] = __builtin_amdgcn_mfma_f32_16x16x32_bf16(
                    a[mi], bb[ni], acc[mi][ni], 0, 0, 0);
        __builtin_amdgcn_s_setprio(0);
    }
#undef STAGE4

    float* outB = out + (size_t)b * (C_OUT_ * T_OUT);
    #pragma unroll
    for (int mi = 0; mi < 4; ++mi) {
        #pragma unroll
        for (int r = 0; r < 4; ++r) {
            int o = wm * 64 + mi * 16 + lg * 4 + r;
            float bv = bias[o];
            #pragma unroll
            for (int ni = 0; ni < 4; ++ni) {
                int n = nt0 + wn * 64 + ni * 16 + l15;
                if (n < NTRIP)
                    outB[o * T_OUT + 1 + n] = acc[mi][ni][r] + bv;
            }
        }
    }
}

// ===================== TIER 1/0 (round-2 fallback) =====================
#define BN      64
#define BK      96
#define NCHUNK  8
#define AS_OFF  0
#define BS_OFF  49152
#define IDX_OFF 61440
#define SMEM_BYTES 62208

template<bool PREW>
__global__ __launch_bounds__(THREADS, 4) void treeconv_mfma(
    const float* __restrict__ data,
    const int*   __restrict__ indexes,
    const float* __restrict__ w32,
    const unsigned short* __restrict__ wbf,
    const float* __restrict__ bias,
    float*       __restrict__ out)
{
    __shared__ alignas(16) unsigned char smem[SMEM_BYTES];
    int* idx_s = (int*)(smem + IDX_OFF);

    const int tid = threadIdx.x;
    const int b   = blockIdx.x >> 4;
    const int nt0 = (blockIdx.x & 15) * BN;

    if (tid < BN * 3) {
        int off = nt0 * 3 + tid;
        idx_s[tid] = (off < L_) ? indexes[b * L_ + off] : 0;
    }
    __syncthreads();

    const int lane = tid & 63;
    const int wid  = tid >> 6;
    const int wm   = wid >> 1;
    const int wn   = wid & 1;
    const int l15  = lane & 15;
    const int lg   = lane >> 4;

    f32x4 acc[4][2];
    #pragma unroll
    for (int mi = 0; mi < 4; ++mi)
        #pragma unroll
        for (int ni = 0; ni < 2; ++ni)
            acc[mi][ni] = (f32x4){0.f, 0.f, 0.f, 0.f};

    const float* dataB = data + (size_t)b * (C_IN_ * NPTS);
    const int ar = tid >> 1;
    const int ah = tid & 1;
    const int gn = tid & 63;
    const int g8 = tid >> 6;

    for (int kc = 0; kc < NCHUNK; ++kc) {
        {
            const int ab = ar * 192 + ah * 96;
            const int sw = (ar & 7) << 4;
            if (PREW) {
                const ushort8* src = (const ushort8*)(wbf + ar * KTOT + kc * BK + ah * 48);
                #pragma unroll
                for (int j = 0; j < 6; ++j) {
                    ushort8 v = src[j];
                    *(ushort8*)(smem + ((ab + j * 16) ^ sw)) = v;
                }
            } else {
                const float* src = w32 + ar * KTOT + kc * BK + ah * 48;
                #pragma unroll
                for (int j = 0; j < 6; ++j) {
                    float4 fa = *(const float4*)(src + j * 8);
                    float4 fb = *(const float4*)(src + j * 8 + 4);
                    ushort8 v;
                    v[0] = f2bf(fa.x); v[1] = f2bf(fa.y); v[2] = f2bf(fa.z); v[3] = f2bf(fa.w);
                    v[4] = f2bf(fb.x); v[5] = f2bf(fb.y); v[6] = f2bf(fb.z); v[7] = f2bf(fb.w);
                    *(ushort8*)(smem + ((ab + j * 16) ^ sw)) = v;
                }
            }
        }
        {
            const int* ip = idx_s + gn * 3;
            int ix0 = ip[0], ix1 = ip[1], ix2 = ip[2];
            const float* dp = dataB + (kc * 32 + g8 * 4) * NPTS;
            unsigned short vals[12];
            #pragma unroll
            for (int ci = 0; ci < 4; ++ci) {
                vals[ci * 3 + 0] = f2bf(dp[ix0]);
                vals[ci * 3 + 1] = f2bf(dp[ix1]);
                vals[ci * 3 + 2] = f2bf(dp[ix2]);
                dp += NPTS;
            }
            const int bb = BS_OFF + gn * 192 + g8 * 24;
            const int sw = (gn & 7) << 4;
            #pragma unroll
            for (int q = 0; q < 3; ++q) {
                ushort4v v;
                v[0] = vals[q * 4 + 0]; v[1] = vals[q * 4 + 1];
                v[2] = vals[q * 4 + 2]; v[3] = vals[q * 4 + 3];
                *(ushort4v*)(smem + ((bb + q * 8) ^ sw)) = v;
            }
        }
        __syncthreads();

        #pragma unroll
        for (int ks = 0; ks < 3; ++ks) {
            bf16x8 a[4], bf[2];
            const int kb = ks * 64 + lg * 16;
            #pragma unroll
            for (int mi = 0; mi < 4; ++mi) {
                int row = wm * 64 + mi * 16 + l15;
                a[mi] = *(const bf16x8*)(smem + ((row * 192 + kb) ^ ((row & 7) << 4)));
            }
            #pragma unroll
            for (int ni = 0; ni < 2; ++ni) {
                int row = wn * 32 + ni * 16 + l15;
                bf[ni] = *(const bf16x8*)(smem + ((BS_OFF + row * 192 + kb) ^ ((row & 7) << 4)));
            }
            #pragma unroll
            for (int mi = 0; mi < 4; ++mi)
                #pragma unroll
                for (int ni = 0; ni < 2; ++ni)
                    acc[mi][ni] = __builtin_amdgcn_mfma_f32_16x16x32_bf16(
                        a[mi], bf[ni], acc[mi][ni], 0, 0, 0);
        }
        __syncthreads();
    }

    float* outB = out + (size_t)b * (C_OUT_ * T_OUT);
    #pragma unroll
    for (int mi = 0; mi < 4; ++mi) {
        #pragma unroll
        for (int r = 0; r < 4; ++r) {
            int o = wm * 64 + mi * 16 + lg * 4 + r;
            float bv = bias[o];
            #pragma unroll
            for (int ni = 0; ni < 2; ++ni) {
                int n = nt0 + wn * 32 + ni * 16 + l15;
                if (n < NTRIP)
                    outB[o * T_OUT + 1 + n] = acc[mi][ni][r] + bv;
            }
        }
    }
}

__global__ __launch_bounds__(256) void convert_w(
    const float* __restrict__ w, unsigned short* __restrict__ wbf)
{
    int i = (blockIdx.x * 256 + threadIdx.x) * 4;
    if (i < C_OUT_ * KTOT) {
        float4 f = *(const float4*)(w + i);
        ushort4v v;
        v[0] = f2bf(f.x); v[1] = f2bf(f.y); v[2] = f2bf(f.z); v[3] = f2bf(f.w);
        *(ushort4v*)(wbf + i) = v;
    }
}

__global__ __launch_bounds__(256) void aux_kernel(
    const int* __restrict__ indexes, float* __restrict__ out)
{
    int i = blockIdx.x * 256 + threadIdx.x;
    if (i < B_ * L_)
        out[FEATS_SIZE + i] = (float)indexes[i];
    if (i < B_ * C_OUT_)
        out[(size_t)i * T_OUT] = 0.0f;
}

extern "C" void kernel_launch(void* const* d_in, const int* in_sizes, int n_in,
                              void* d_out, int out_size, void* d_ws, size_t ws_size,
                              hipStream_t stream)
{
    const float* data    = (const float*)d_in[0];
    const int*   indexes = (const int*)d_in[1];
    const float* weight  = (const float*)d_in[2];
    const float* bias    = (const float*)d_in[3];
    float* out = (float*)d_out;

    hipLaunchKernelGGL(aux_kernel, dim3((B_ * L_ + 255) / 256), dim3(256), 0, stream,
                       indexes, out);

    if (ws_size >= (size_t)WS_NEED_T2) {
        unsigned short* wbf4  = (unsigned short*)((char*)d_ws + WOFF_T);
        unsigned short* dataT = (unsigned short*)((char*)d_ws + DOFF_T);
        hipLaunchKernelGGL(convert_w4, dim3((C_OUT_ * KTOT + 255) / 256), dim3(256),
                           0, stream, weight, wbf4);
        hipLaunchKernelGGL(transpose_data, dim3(B_ * 64), dim3(256), 0, stream,
                           data, dataT);
        hipLaunchKernelGGL(treeconv_mfma4, dim3(B_ * 8), dim3(THREADS), 0, stream,
                           wbf4, dataT, indexes, bias, out);
    } else if (ws_size >= (size_t)(C_OUT_ * KTOT * 2)) {
        unsigned short* wbf = (unsigned short*)d_ws;
        hipLaunchKernelGGL(convert_w, dim3((C_OUT_ * KTOT / 4 + 255) / 256), dim3(256),
                           0, stream, weight, wbf);
        hipLaunchKernelGGL((treeconv_mfma<true>), dim3(B_ * 16), dim3(THREADS), 0, stream,
                           data, indexes, weight, wbf, bias, out);
    } else {
        hipLaunchKernelGGL((treeconv_mfma<false>), dim3(B_ * 16), dim3(THREADS), 0, stream,
                           data, indexes, weight, (const unsigned short*)d_ws, bias, out);
    }
}